// Round 1
// baseline (394.096 us; speedup 1.0000x reference)
//
#include <hip/hip_runtime.h>

// GraphSAGE (2x SAGEConv mean + global_mean_pool + linear) collapsed algebraically:
// out = ((St@W1l + Sw@W1r + Wsum*b1) @ W2l + (Sw@W1l + Sx@W1r + N*b1) @ W2r)/N + b2) @ Wout + bout
// where d_i = max(indeg_i,1), ws_j = sum_{e:src=j} 1/d[dst_e], u_j = ws_j/d_j,
// t_k = sum_{e:src=k} u[dst_e], Sx = sum_k x_k, Sw = sum_k ws_k x_k, St = sum_k t_k x_k.

#define NN   100000
#define NE   1600000
#define FEAT 128
#define NCLS 40

__global__ __launch_bounds__(256) void k_count(const int* __restrict__ dst, int* __restrict__ cnt) {
    int i = blockIdx.x * 256 + threadIdx.x;
    if (i < NE) atomicAdd(&cnt[dst[i]], 1);
}

__global__ __launch_bounds__(256) void k_ws(const int* __restrict__ src, const int* __restrict__ dst,
                                            const int* __restrict__ cnt, float* __restrict__ ws) {
    int i = blockIdx.x * 256 + threadIdx.x;
    if (i < NE) {
        int c = cnt[dst[i]];                  // >= 1 by construction (this edge counts)
        atomicAdd(&ws[src[i]], 1.0f / (float)c);
    }
}

__global__ __launch_bounds__(256) void k_u(const int* __restrict__ cnt, const float* __restrict__ ws,
                                           float* __restrict__ u) {
    int i = blockIdx.x * 256 + threadIdx.x;
    if (i < NN) {
        int c = cnt[i];
        u[i] = ws[i] / (float)(c > 0 ? c : 1);
    }
}

__global__ __launch_bounds__(256) void k_t(const int* __restrict__ src, const int* __restrict__ dst,
                                           const float* __restrict__ u, float* __restrict__ t) {
    int i = blockIdx.x * 256 + threadIdx.x;
    if (i < NE) atomicAdd(&t[src[i]], u[dst[i]]);
}

// Three weighted feature sums over x [NN,128] in one pass.
// Block = 256 threads: 8 row-groups x 32 lanes; lane covers features [4*lane, 4*lane+4) as float4.
__global__ __launch_bounds__(256) void k_featsums(const float* __restrict__ x,
                                                  const float* __restrict__ ws,
                                                  const float* __restrict__ t,
                                                  float* __restrict__ sums) {
    int lane = threadIdx.x & 31;
    int grp  = threadIdx.x >> 5;          // 0..7
    int row0 = blockIdx.x * 8 + grp;
    int rstride = gridDim.x * 8;

    float sx0=0,sx1=0,sx2=0,sx3=0;
    float sw0=0,sw1=0,sw2=0,sw3=0;
    float st0=0,st1=0,st2=0,st3=0;
    float wsum = 0.f;

    for (int r = row0; r < NN; r += rstride) {
        const float4* xr = (const float4*)(x + (size_t)r * FEAT);
        float4 v = xr[lane];
        float wr = ws[r];
        float tr = t[r];
        sx0 += v.x; sx1 += v.y; sx2 += v.z; sx3 += v.w;
        sw0 += wr*v.x; sw1 += wr*v.y; sw2 += wr*v.z; sw3 += wr*v.w;
        st0 += tr*v.x; st1 += tr*v.y; st2 += tr*v.z; st3 += tr*v.w;
        if (lane == 0) wsum += wr;
    }

    __shared__ float shx[8][32][4];
    __shared__ float shw[8][32][4];
    __shared__ float sht[8][32][4];
    __shared__ float shwsum[8];
    shx[grp][lane][0]=sx0; shx[grp][lane][1]=sx1; shx[grp][lane][2]=sx2; shx[grp][lane][3]=sx3;
    shw[grp][lane][0]=sw0; shw[grp][lane][1]=sw1; shw[grp][lane][2]=sw2; shw[grp][lane][3]=sw3;
    sht[grp][lane][0]=st0; sht[grp][lane][1]=st1; sht[grp][lane][2]=st2; sht[grp][lane][3]=st3;
    if (lane == 0) shwsum[grp] = wsum;
    __syncthreads();

    if (grp == 0) {
        float ax[4], aw[4], at[4];
        #pragma unroll
        for (int c = 0; c < 4; ++c) { ax[c]=shx[0][lane][c]; aw[c]=shw[0][lane][c]; at[c]=sht[0][lane][c]; }
        #pragma unroll
        for (int g = 1; g < 8; ++g) {
            #pragma unroll
            for (int c = 0; c < 4; ++c) {
                ax[c]+=shx[g][lane][c]; aw[c]+=shw[g][lane][c]; at[c]+=sht[g][lane][c];
            }
        }
        #pragma unroll
        for (int c = 0; c < 4; ++c) {
            atomicAdd(&sums[        4*lane + c], ax[c]);
            atomicAdd(&sums[FEAT  + 4*lane + c], aw[c]);
            atomicAdd(&sums[2*FEAT+ 4*lane + c], at[c]);
        }
        if (lane == 0) {
            float w = shwsum[0];
            #pragma unroll
            for (int g = 1; g < 8; ++g) w += shwsum[g];
            atomicAdd(&sums[3*FEAT], w);
        }
    }
}

// Single-block epilogue: small matvecs with 128x128 weights, then 128x40 head.
__global__ __launch_bounds__(128) void k_final(const float* __restrict__ sums,
                                               const float* __restrict__ W1l, const float* __restrict__ W1r,
                                               const float* __restrict__ b1,
                                               const float* __restrict__ W2l, const float* __restrict__ W2r,
                                               const float* __restrict__ b2,
                                               const float* __restrict__ Wout, const float* __restrict__ bout,
                                               float* __restrict__ out) {
    __shared__ float Sx[FEAT], Sw[FEAT], St[FEAT], M1[FEAT], S2[FEAT], G[FEAT];
    __shared__ float Wsum;
    int f = threadIdx.x;
    Sx[f] = sums[f];
    Sw[f] = sums[FEAT + f];
    St[f] = sums[2*FEAT + f];
    if (f == 0) Wsum = sums[3*FEAT];
    __syncthreads();

    float m1 = (float)NN * b1[f];
    float s2 = Wsum * b1[f];
    for (int k = 0; k < FEAT; ++k) {
        float wl = W1l[k*FEAT + f];
        float wr = W1r[k*FEAT + f];
        m1 += Sw[k]*wl + Sx[k]*wr;
        s2 += St[k]*wl + Sw[k]*wr;
    }
    M1[f] = m1; S2[f] = s2;
    __syncthreads();

    float g = 0.f;
    for (int k = 0; k < FEAT; ++k)
        g += S2[k]*W2l[k*FEAT + f] + M1[k]*W2r[k*FEAT + f];
    g = g * (1.0f/(float)NN) + b2[f];
    G[f] = g;
    __syncthreads();

    if (f < NCLS) {
        float o = bout[f];
        for (int k = 0; k < FEAT; ++k)
            o += G[k]*Wout[k*NCLS + f];
        out[f] = o;
    }
}

extern "C" void kernel_launch(void* const* d_in, const int* in_sizes, int n_in,
                              void* d_out, int out_size, void* d_ws, size_t ws_size,
                              hipStream_t stream) {
    const float* x    = (const float*)d_in[0];
    const int*   ei   = (const int*)d_in[1];     // [2, NE] flat: src then dst
    const float* W1l  = (const float*)d_in[2];
    const float* W1r  = (const float*)d_in[3];
    const float* b1   = (const float*)d_in[4];
    const float* W2l  = (const float*)d_in[5];
    const float* W2r  = (const float*)d_in[6];
    const float* b2   = (const float*)d_in[7];
    const float* Wout = (const float*)d_in[8];
    const float* bout = (const float*)d_in[9];
    float* out = (float*)d_out;

    const int* src = ei;
    const int* dst = ei + NE;

    int*   cnt  = (int*)d_ws;                       // [NN]
    float* ws   = (float*)d_ws + NN;                // [NN]
    float* t    = (float*)d_ws + 2*NN;              // [NN]
    float* sums = (float*)d_ws + 3*NN;              // [3*FEAT + 1]
    float* u    = (float*)d_ws + 3*NN + 512;        // [NN] (no init needed, fully written)

    // zero cnt, ws, t, sums (workspace is poisoned 0xAA before every call)
    hipMemsetAsync(d_ws, 0, (size_t)(3*NN + 3*FEAT + 1) * 4, stream);

    const int EB = (NE + 255) / 256;
    const int NB = (NN + 255) / 256;
    k_count<<<EB, 256, 0, stream>>>(dst, cnt);
    k_ws<<<EB, 256, 0, stream>>>(src, dst, cnt, ws);
    k_u<<<NB, 256, 0, stream>>>(cnt, ws, u);
    k_t<<<EB, 256, 0, stream>>>(src, dst, u, t);
    k_featsums<<<256, 256, 0, stream>>>(x, ws, t, sums);
    k_final<<<1, 128, 0, stream>>>(sums, W1l, W1r, b1, W2l, W2r, b2, Wout, bout, out);
}